// Round 1
// baseline (544.308 us; speedup 1.0000x reference)
//
#include <hip/hip_runtime.h>
#include <hip/hip_bf16.h>
#include <cstddef>

// ---------------------------------------------------------------------------
// GNN layer (RED-GNN style), MI355X.
// Outputs (concatenated fp32 in d_out):
//   hidden_new [N_NODE*64] | alpha [N_EDGE] | message [N_EDGE*64]
//   | obj(as float) [N_EDGE] | alpha_temp [N_EDGE]
// Strategy: factor the three 64x64 matvecs out of the edge loop:
//   hsWs = hidden @ Ws           (per-node, 100K x 64)
//   B_r  = rela_embed @ Wr       (per-relation, 401 x 64)
//   C_q  = rela_embed[q_rel]@Wqr + b  (per-query, 256 x 64)
// Edge kernel: 1 wave per edge, lane = feature dim. Wave-shuffle reduce for
// the w_alpha dot; atomicAdd scatter into agg; final matmul agg @ W_h.
// ---------------------------------------------------------------------------

// Y[row] = X[row] @ W (+ bias), X: nrows x 64, W: 64 x 64 in LDS.
// block = 256 threads = 4 rows x 64 cols.
__global__ void matmul64_kernel(const float* __restrict__ X,
                                const float* __restrict__ W,
                                const float* __restrict__ bias,
                                float* __restrict__ Y, int nrows) {
    __shared__ float Wl[64][64];
    int tid = threadIdx.x;
    for (int i = tid; i < 4096; i += 256) Wl[i >> 6][i & 63] = W[i];
    __syncthreads();
    int col = tid & 63;
    int r4  = tid >> 6;
    for (long row = (long)blockIdx.x * 4 + r4; row < nrows;
         row += (long)gridDim.x * 4) {
        float xv  = X[row * 64 + col];           // coalesced row load
        float acc = bias ? bias[col] : 0.0f;
#pragma unroll
        for (int k = 0; k < 64; ++k)
            acc = fmaf(__shfl(xv, k, 64), Wl[k][col], acc);
        Y[row * 64 + col] = acc;
    }
}

// Precompute B_r = rela@Wr and C_q = rela[q_rel]@Wqr + Wqr_b in one kernel.
__global__ void rel_precompute_kernel(const float* __restrict__ rela,
                                      const float* __restrict__ Wr,
                                      const float* __restrict__ Wqr,
                                      const float* __restrict__ Wqr_b,
                                      const int* __restrict__ q_rel,
                                      float* __restrict__ Br,
                                      float* __restrict__ Cq,
                                      int nrel, int nq) {
    __shared__ float W1[64][64];
    __shared__ float W2[64][64];
    int tid = threadIdx.x;
    for (int i = tid; i < 4096; i += 256) {
        W1[i >> 6][i & 63] = Wr[i];
        W2[i >> 6][i & 63] = Wqr[i];
    }
    __syncthreads();
    int col = tid & 63;
    int r4  = tid >> 6;
    int total = nrel + nq;
    for (int row = blockIdx.x * 4 + r4; row < total; row += gridDim.x * 4) {
        if (row < nrel) {
            float xv  = rela[(size_t)row * 64 + col];
            float acc = 0.0f;
#pragma unroll
            for (int k = 0; k < 64; ++k)
                acc = fmaf(__shfl(xv, k, 64), W1[k][col], acc);
            Br[(size_t)row * 64 + col] = acc;
        } else {
            int q  = row - nrel;
            int rr = q_rel[q];
            float xv  = rela[(size_t)rr * 64 + col];
            float acc = Wqr_b[col];
#pragma unroll
            for (int k = 0; k < 64; ++k)
                acc = fmaf(__shfl(xv, k, 64), W2[k][col], acc);
            Cq[(size_t)q * 64 + col] = acc;
        }
    }
}

// One wave per edge; lane = feature dim (0..63). 4 waves / block.
__global__ void edge_kernel(const int* __restrict__ edges,
                            const float* __restrict__ hidden,
                            const float* __restrict__ rela,
                            const float* __restrict__ hsWs,
                            const float* __restrict__ Br,
                            const float* __restrict__ Cq,
                            const float* __restrict__ w_alpha_w,
                            const float* __restrict__ w_alpha_b,
                            float* __restrict__ agg,
                            float* __restrict__ out_alpha,
                            float* __restrict__ out_message,
                            float* __restrict__ out_obj,
                            float* __restrict__ out_alpha_temp,
                            int nedge) {
    int lane = threadIdx.x & 63;
    long e = (long)blockIdx.x * 4 + (threadIdx.x >> 6);
    if (e >= nedge) return;

    const int* ed = edges + e * 6;
    int r_idx = ed[0];
    int rel   = ed[2];
    int sub   = ed[4];
    int obj   = ed[5];

    float attn = hsWs[(size_t)sub * 64 + lane]
               + Br[(size_t)rel * 64 + lane]
               + Cq[(size_t)r_idx * 64 + lane];
    attn = fmaxf(attn, 0.0f);

    float dot = attn * w_alpha_w[lane];
#pragma unroll
    for (int m = 1; m < 64; m <<= 1) dot += __shfl_xor(dot, m, 64);
    float at    = dot + w_alpha_b[0];
    float alpha = 1.0f / (1.0f + __expf(-at));

    float msg = alpha * (hidden[(size_t)sub * 64 + lane]
                       + rela[(size_t)rel * 64 + lane]);

    out_message[e * 64 + lane] = msg;
    atomicAdd(&agg[(size_t)obj * 64 + lane], msg);

    if (lane == 0) {
        out_alpha[e]      = alpha;
        out_obj[e]        = (float)obj;
        out_alpha_temp[e] = at;
    }
}

extern "C" void kernel_launch(void* const* d_in, const int* in_sizes, int n_in,
                              void* d_out, int out_size, void* d_ws, size_t ws_size,
                              hipStream_t stream) {
    // Input order per setup_inputs():
    // 0 q_sub(int,256) 1 q_rel(int,256) 2 hidden(f32,N*64) 3 edges(int,E*6)
    // 4 n_node(int,1) 5 rela_embed(f32,R*64) 6 Ws 7 Wr 8 Wqr 9 Wqr_b
    // 10 w_alpha_w 11 w_alpha_b 12 W_h
    const int*   q_rel     = (const int*)d_in[1];
    const float* hidden    = (const float*)d_in[2];
    const int*   edges     = (const int*)d_in[3];
    const float* rela      = (const float*)d_in[5];
    const float* Ws        = (const float*)d_in[6];
    const float* Wr        = (const float*)d_in[7];
    const float* Wqr       = (const float*)d_in[8];
    const float* Wqr_b     = (const float*)d_in[9];
    const float* w_alpha_w = (const float*)d_in[10];
    const float* w_alpha_b = (const float*)d_in[11];
    const float* W_h       = (const float*)d_in[12];

    const int n_node = in_sizes[2] / 64;    // 100000
    const int n_edge = in_sizes[3] / 6;     // 1000000
    const int n_rel  = in_sizes[5] / 64;    // 401
    const int n_q    = in_sizes[1];         // 256

    // Output layout (all fp32).
    float* out            = (float*)d_out;
    float* out_hidden_new = out;
    float* out_alpha      = out + (size_t)n_node * 64;
    float* out_message    = out_alpha + n_edge;
    float* out_obj        = out_message + (size_t)n_edge * 64;
    float* out_alpha_temp = out_obj + n_edge;

    // Workspace layout.
    float* hsWs = (float*)d_ws;                        // n_node*64
    float* agg  = hsWs + (size_t)n_node * 64;          // n_node*64
    float* Br   = agg + (size_t)n_node * 64;           // n_rel*64
    float* Cq   = Br + (size_t)n_rel * 64;             // n_q*64

    // Zero the segment-sum accumulator (we atomicAdd into it every call).
    hipMemsetAsync(agg, 0, (size_t)n_node * 64 * sizeof(float), stream);

    // 1) hsWs = hidden @ Ws
    {
        int grid = (n_node + 3) / 4;
        matmul64_kernel<<<grid, 256, 0, stream>>>(hidden, Ws, nullptr, hsWs, n_node);
    }
    // 2) B_r, C_q
    {
        int grid = (n_rel + n_q + 3) / 4;
        rel_precompute_kernel<<<grid, 256, 0, stream>>>(rela, Wr, Wqr, Wqr_b,
                                                        q_rel, Br, Cq, n_rel, n_q);
    }
    // 3) per-edge: attn, alpha, message, scatter into agg
    {
        int grid = (n_edge + 3) / 4;
        edge_kernel<<<grid, 256, 0, stream>>>(edges, hidden, rela, hsWs, Br, Cq,
                                              w_alpha_w, w_alpha_b, agg,
                                              out_alpha, out_message, out_obj,
                                              out_alpha_temp, n_edge);
    }
    // 4) hidden_new = agg @ W_h
    {
        int grid = (n_node + 3) / 4;
        matmul64_kernel<<<grid, 256, 0, stream>>>(agg, W_h, nullptr, out_hidden_new, n_node);
    }
}